// Round 1
// baseline (3485.608 us; speedup 1.0000x reference)
//
#include <hip/hip_runtime.h>
#include <math.h>

#define BATCH 64
#define CIN 16
#define H 256
#define W 256
#define COUT 64
#define KS 3
#define HO 254
#define WO 254

#define TS 16   // output tile edge
#define TIN 18  // input tile edge = TS + KS - 1

__global__ __launch_bounds__(256, 2)
void conv_min_tanh_f32(const float* __restrict__ x,
                       const float* __restrict__ w,
                       const float* __restrict__ bias,
                       float* __restrict__ out) {
    __shared__ float xs[CIN][TIN][TIN];

    const int b      = blockIdx.z;
    const int tile_y = blockIdx.y * TS;
    const int tile_x = blockIdx.x * TS;
    const int tid    = threadIdx.x;
    const int tx     = tid & 15;
    const int ty     = tid >> 4;

    // ---- stage input tile (16 cin x 18 x 18) into LDS, zero-padded at edges ----
    const float* xb = x + (size_t)b * CIN * H * W;
    for (int idx = tid; idx < CIN * TIN * TIN; idx += 256) {
        int ci = idx / (TIN * TIN);
        int r  = (idx / TIN) % TIN;
        int c  = idx % TIN;
        int gy = tile_y + r;
        int gx = tile_x + c;
        float v = 0.0f;
        if (gy < H && gx < W) v = xb[(size_t)ci * (H * W) + gy * W + gx];
        xs[ci][r][c] = v;
    }
    __syncthreads();

    // ---- init accumulators with bias (scalar loads: uniform index) ----
    float acc[COUT];
    #pragma unroll
    for (int c = 0; c < COUT; ++c) acc[c] = bias[c];

    // ---- main loop: cin in chunks of 4; weights via wave-uniform global reads
    //      (compiler scalarizes to s_load + SGPR-operand v_fma_f32) ----
    for (int cb = 0; cb < CIN; cb += 4) {
        float xr[4][KS][KS];
        #pragma unroll
        for (int ci = 0; ci < 4; ++ci)
            #pragma unroll
            for (int kh = 0; kh < KS; ++kh)
                #pragma unroll
                for (int kw = 0; kw < KS; ++kw)
                    xr[ci][kh][kw] = xs[cb + ci][ty + kh][tx + kw];

        #pragma unroll
        for (int c = 0; c < COUT; ++c) {
            float a = acc[c];
            const float* wc = w + ((size_t)c * CIN + cb) * (KS * KS);
            #pragma unroll
            for (int ci = 0; ci < 4; ++ci)
                #pragma unroll
                for (int kh = 0; kh < KS; ++kh)
                    #pragma unroll
                    for (int kw = 0; kw < KS; ++kw)
                        a = fmaf(xr[ci][kh][kw], wc[(ci * KS + kh) * KS + kw], a);
            acc[c] = a;
        }
    }

    // ---- min over channels, double tanh, store ----
    float m = acc[0];
    #pragma unroll
    for (int c = 1; c < COUT; ++c) m = fminf(m, acc[c]);
    float r = tanhf(tanhf(m));

    const int oy = tile_y + ty;
    const int ox = tile_x + tx;
    if (oy < HO && ox < WO)
        out[((size_t)b * HO + oy) * WO + ox] = r;
}

extern "C" void kernel_launch(void* const* d_in, const int* in_sizes, int n_in,
                              void* d_out, int out_size, void* d_ws, size_t ws_size,
                              hipStream_t stream) {
    const float* x    = (const float*)d_in[0];
    const float* w    = (const float*)d_in[1];
    const float* bias = (const float*)d_in[2];
    float* out        = (float*)d_out;

    dim3 grid((WO + TS - 1) / TS, (HO + TS - 1) / TS, BATCH);  // 16 x 16 x 64
    dim3 block(256);
    hipLaunchKernelGGL(conv_min_tanh_f32, grid, block, 0, stream, x, w, bias, out);
}

// Round 2
// 215.239 us; speedup vs baseline: 16.1941x; 16.1941x over previous
//
#include <hip/hip_runtime.h>
#include <hip/hip_bf16.h>
#include <math.h>

#define BATCH 64
#define CIN   16
#define H     256
#define W     256
#define COUT  64
#define HO    254
#define WO    254

#define TS    16          // output tile edge per block (16x16 px)
#define TIN   18          // staged input tile edge
#define CELL  24          // ushorts per (y,x) LDS cell: 16 ci + 8 pad -> 48B stride (2-way bank alias only)

typedef short  bf16x8 __attribute__((ext_vector_type(8)));   // 8 bf16 in 4 VGPRs (guide §3 convention)
typedef float  f32x16 __attribute__((ext_vector_type(16)));

static __device__ __forceinline__ unsigned short bfbits(float f) {
    __hip_bfloat16 h = __float2bfloat16(f);
    return *(unsigned short*)&h;
}

static __device__ __forceinline__ bf16x8 ld_frag(const ushort* p) {
    union { uint4 u; bf16x8 b; } cv;
    cv.u = *(const uint4*)p;
    return cv.b;
}

// ---- repack weights: w[cout][ci][kh][kw] fp32 -> wpk[tap][cout][ci] bf16 ----
__global__ void repack_w(const float* __restrict__ w, ushort* __restrict__ wpk) {
    int i = blockIdx.x * 256 + threadIdx.x;
    if (i < 9 * COUT * CIN) {
        int ci   = i & 15;
        int cout = (i >> 4) & 63;
        int tap  = i >> 10;
        wpk[i] = bfbits(w[(cout * CIN + ci) * 9 + tap]);
    }
}

__global__ __launch_bounds__(256)
void conv_min_tanh_mfma(const float* __restrict__ x,
                        const float* __restrict__ bias,
                        const ushort* __restrict__ wpk,
                        float* __restrict__ out) {
    __shared__ __align__(16) ushort xs[TIN * TIN * CELL];   // 15552 B
    __shared__ __align__(16) float  omin[4][64];            // 1024 B

    const int b    = blockIdx.z;
    const int y0   = blockIdx.y * TS;
    const int x0   = blockIdx.x * TS;
    const int tid  = threadIdx.x;
    const int lane = tid & 63;
    const int wv   = tid >> 6;
    const int l31  = lane & 31;
    const int hi   = lane >> 5;   // k-group: ci 0-7 vs 8-15

    // ---- B fragments (weights), loop-invariant, from L2-resident d_ws ----
    bf16x8 bw[9][2];
    #pragma unroll
    for (int tap = 0; tap < 9; ++tap)
        #pragma unroll
        for (int nt = 0; nt < 2; ++nt)
            bw[tap][nt] = ld_frag(wpk + tap * 1024 + (nt * 32 + l31) * 16 + hi * 8);

    // ---- accumulators init with per-cout bias (D col = cout = l31 + nt*32) ----
    const float b0 = bias[l31];
    const float b1 = bias[32 + l31];
    f32x16 acc[2][2];
    #pragma unroll
    for (int r = 0; r < 16; ++r) {
        acc[0][0][r] = b0; acc[1][0][r] = b0;
        acc[0][1][r] = b1; acc[1][1][r] = b1;
    }

    // ---- stage x tile: [y][x][ci] bf16, 4 ci per thread-item (b64 LDS writes) ----
    const float* xb = x + (size_t)b * (CIN * H * W);
    for (int it = tid; it < 4 * TIN * TIN; it += 256) {
        int xl = it % TIN;
        int yl = (it / TIN) % TIN;
        int cg = it / (TIN * TIN);          // ci group of 4
        int gy = min(y0 + yl, H - 1);       // clamp: OOB values only feed discarded px
        int gx = min(x0 + xl, W - 1);
        const float* p = xb + ((size_t)(cg * 4) * H + gy) * W + gx;
        ushort4 v;
        v.x = bfbits(p[0]);
        v.y = bfbits(p[H * W]);
        v.z = bfbits(p[2 * H * W]);
        v.w = bfbits(p[3 * H * W]);
        *(ushort4*)&xs[(yl * TIN + xl) * CELL + cg * 4] = v;
    }
    __syncthreads();

    // ---- main: 9 taps, one 32x32x16 MFMA per (Mtile,Ntile,tap) ----
    // A row = pixel: py = wv*4 + m*2 + (l31>>4), px = l31&15 ; k = ci = hi*8+j
    const int py0 = wv * 4 + (l31 >> 4);
    const int px  = l31 & 15;
    const ushort* abase = xs + (py0 * TIN + px) * CELL + hi * 8;
    #pragma unroll
    for (int tap = 0; tap < 9; ++tap) {
        const int kh = tap / 3, kw = tap - 3 * kh;
        const int toff = (kh * TIN + kw) * CELL;
        bf16x8 a0 = ld_frag(abase + toff);                      // Mtile 0
        bf16x8 a1 = ld_frag(abase + 2 * TIN * CELL + toff);     // Mtile 1 (+2 rows)
        acc[0][0] = __builtin_amdgcn_mfma_f32_32x32x16_bf16(a0, bw[tap][0], acc[0][0], 0, 0, 0);
        acc[0][1] = __builtin_amdgcn_mfma_f32_32x32x16_bf16(a0, bw[tap][1], acc[0][1], 0, 0, 0);
        acc[1][0] = __builtin_amdgcn_mfma_f32_32x32x16_bf16(a1, bw[tap][0], acc[1][0], 0, 0, 0);
        acc[1][1] = __builtin_amdgcn_mfma_f32_32x32x16_bf16(a1, bw[tap][1], acc[1][1], 0, 0, 0);
    }

    // ---- epilogue: min over couts, tanh(tanh()), store ----
    // D layout: col(=cout) = l31, row = (reg&3) + 8*(reg>>2) + 4*hi
    #pragma unroll
    for (int m = 0; m < 2; ++m) {
        float v[16];
        #pragma unroll
        for (int r = 0; r < 16; ++r)
            v[r] = fminf(acc[m][0][r], acc[m][1][r]);           // min over the 2 Ntiles
        #pragma unroll
        for (int off = 1; off <= 16; off <<= 1)
            #pragma unroll
            for (int r = 0; r < 16; ++r)
                v[r] = fminf(v[r], __shfl_xor(v[r], off, 64));  // min across 32 couts (same hi)
        if (l31 == 0) {
            #pragma unroll
            for (int g = 0; g < 4; ++g) {                        // regs 4g..4g+3 -> rows 8g+4*hi..+3
                float4 f4 = make_float4(v[4 * g], v[4 * g + 1], v[4 * g + 2], v[4 * g + 3]);
                *(float4*)&omin[wv][m * 32 + g * 8 + hi * 4] = f4;
            }
        }
    }
    __syncthreads();
    {
        float val = omin[wv][lane];
        int m  = lane >> 5;
        int r  = lane & 31;
        int py = wv * 4 + m * 2 + (r >> 4);
        int pxo = r & 15;
        int oy = y0 + py, ox = x0 + pxo;
        if (oy < HO && ox < WO)
            out[((size_t)b * HO + oy) * WO + ox] = tanhf(tanhf(val));
    }
}

extern "C" void kernel_launch(void* const* d_in, const int* in_sizes, int n_in,
                              void* d_out, int out_size, void* d_ws, size_t ws_size,
                              hipStream_t stream) {
    const float* x    = (const float*)d_in[0];
    const float* w    = (const float*)d_in[1];
    const float* bias = (const float*)d_in[2];
    float* out        = (float*)d_out;
    ushort* wpk       = (ushort*)d_ws;   // 9*64*16 bf16 = 18432 B

    hipLaunchKernelGGL(repack_w, dim3(36), dim3(256), 0, stream, w, wpk);

    dim3 grid((WO + TS - 1) / TS, (HO + TS - 1) / TS, BATCH);   // 16 x 16 x 64
    hipLaunchKernelGGL(conv_min_tanh_mfma, grid, dim3(256), 0, stream,
                       x, bias, wpk, out);
}

// Round 3
// 128.436 us; speedup vs baseline: 27.1389x; 1.6758x over previous
//
#include <hip/hip_runtime.h>
#include <hip/hip_bf16.h>

#define BATCH 64
#define CIN   16
#define H     256
#define W     256
#define HW    (H*W)
#define COUT  64
#define HO    254
#define WO    254

#define TS     16          // output tile edge
#define TIN    18          // staged input tile edge
#define CELL   24          // ushorts per (y,x) cell: 16 ci + 8 pad (48B stride)
#define NTY    16          // y-tiles per strip block
#define NITEMS (4*TIN*TIN) // staging items per tile (4 ci-groups x 18 x 18)
#define IPT    6           // max items per thread

typedef short  bf16x8 __attribute__((ext_vector_type(8)));
typedef float  f32x16 __attribute__((ext_vector_type(16)));

static __device__ __forceinline__ unsigned short bfbits(float f) {
    __hip_bfloat16 h = __float2bfloat16(f);
    return *(unsigned short*)&h;
}

static __device__ __forceinline__ bf16x8 ld_frag(const ushort* p) {
    union { uint4 u; bf16x8 b; } cv;
    cv.u = *(const uint4*)p;
    return cv.b;
}

static __device__ __forceinline__ float fast_tanh(float x) {
    // tanh(x) = (e^2x - 1)/(e^2x + 1); clamp so exp2 can't overflow
    x = fminf(fmaxf(x, -15.f), 15.f);
    float e = __expf(2.f * x);
    return (e - 1.f) * __builtin_amdgcn_rcpf(e + 1.f);
}

// ---- repack weights: w[cout][ci][kh][kw] fp32 -> wpk[tap][cout][ci] bf16 ----
__global__ void repack_w(const float* __restrict__ w, ushort* __restrict__ wpk) {
    int i = blockIdx.x * 256 + threadIdx.x;
    if (i < 9 * COUT * CIN) {
        int ci   = i & 15;
        int cout = (i >> 4) & 63;
        int tap  = i >> 10;
        wpk[i] = bfbits(w[(cout * CIN + ci) * 9 + tap]);
    }
}

// One block = one x-strip of one batch image: marches down 16 y-tiles with
// double-buffered LDS staging (T14 split: loads issued before compute, LDS
// writes after). M = couts (A = weights), N = pixels (B = x) so the 64-cout
// min is in-register + one shfl_xor(32).
__global__ __launch_bounds__(256, 2)
void conv_min_tanh_strip(const float* __restrict__ x,
                         const float* __restrict__ bias,
                         const ushort* __restrict__ wpk,
                         float* __restrict__ out) {
    __shared__ __align__(16) ushort xsm[2][TIN * TIN * CELL];  // 2 x 15552 B

    // XCD-friendly remap: all 16 strips of a batch land on one XCD chunk
    const int bid    = blockIdx.x;                 // 0..1023
    const int L      = (bid & 7) * 128 + (bid >> 3);
    const int xstrip = L & 15;
    const int b      = L >> 4;
    const int x0     = xstrip * TS;

    const int tid  = threadIdx.x;
    const int lane = tid & 63;
    const int wv   = tid >> 6;
    const int l31  = lane & 31;
    const int hi   = lane >> 5;       // k half: ci 0-7 vs 8-15 ; also D row +4*hi

    const float* xb = x + (size_t)b * (CIN * HW);

    // per-accumulator-register bias values (D row = cout = (r&3)+8*(r>>2)+4*hi + m*32)
    float bini[2][16];
    #pragma unroll
    for (int m = 0; m < 2; ++m)
        #pragma unroll
        for (int r = 0; r < 16; ++r)
            bini[m][r] = bias[m * 32 + (r & 3) + 8 * (r >> 2) + 4 * hi];

    // B-frag (pixel) cell bases, ushort units. N-tile n: col = pixel l31,
    // py = wv*4 + n*2 + (l31>>4), px = l31&15, k = ci = hi*8+j
    const int py_b = wv * 4 + (l31 >> 4);
    const int pxc  = l31 & 15;
    const int cb0  = ((py_b + 0) * TIN + pxc) * CELL + hi * 8;
    const int cb1  = ((py_b + 2) * TIN + pxc) * CELL + hi * 8;

    float fx[IPT][4];

    // ---- staging helpers ----
    auto stage_load = [&](int ty) {
        const int ybase = ty * TS;
        #pragma unroll
        for (int k = 0; k < IPT; ++k) {
            int it = tid + k * 256;
            if (it < NITEMS) {
                int dx = it % TIN;
                int t2 = it / TIN;
                int dy = t2 % TIN;
                int cg = t2 / TIN;
                int gy = min(ybase + dy, H - 1);
                int gx = min(x0 + dx, W - 1);
                const float* p = xb + (size_t)(cg * 4) * HW + gy * W + gx;
                fx[k][0] = p[0];
                fx[k][1] = p[HW];
                fx[k][2] = p[2 * HW];
                fx[k][3] = p[3 * HW];
            }
        }
    };
    auto stage_write = [&](int buf) {
        #pragma unroll
        for (int k = 0; k < IPT; ++k) {
            int it = tid + k * 256;
            if (it < NITEMS) {
                int dx = it % TIN;
                int t2 = it / TIN;
                int dy = t2 % TIN;
                int cg = t2 / TIN;
                ushort4 v;
                v.x = bfbits(fx[k][0]);
                v.y = bfbits(fx[k][1]);
                v.z = bfbits(fx[k][2]);
                v.w = bfbits(fx[k][3]);
                *(ushort4*)&xsm[buf][(dy * TIN + dx) * CELL + cg * 4] = v;
            }
        }
    };

    // ---- prologue: stage tile 0 ----
    stage_load(0);
    stage_write(0);
    __syncthreads();

    for (int ty = 0; ty < NTY; ++ty) {
        const int cur = ty & 1;

        // T14: issue next tile's global loads before compute
        if (ty + 1 < NTY) stage_load(ty + 1);

        // ---- compute current tile ----
        f32x16 acc[2][2];
        #pragma unroll
        for (int m = 0; m < 2; ++m)
            #pragma unroll
            for (int r = 0; r < 16; ++r) {
                acc[m][0][r] = bini[m][r];
                acc[m][1][r] = bini[m][r];
            }

        const ushort* xt = &xsm[cur][0];
        #pragma unroll
        for (int tap = 0; tap < 9; ++tap) {
            const int kh = tap / 3, kw = tap - 3 * kh;
            const int toff = (kh * TIN + kw) * CELL;
            bf16x8 p0 = ld_frag(xt + cb0 + toff);
            bf16x8 p1 = ld_frag(xt + cb1 + toff);
            bf16x8 w0 = ld_frag(wpk + tap * 1024 + l31 * 16 + hi * 8);          // couts 0-31
            bf16x8 w1 = ld_frag(wpk + tap * 1024 + (32 + l31) * 16 + hi * 8);   // couts 32-63
            acc[0][0] = __builtin_amdgcn_mfma_f32_32x32x16_bf16(w0, p0, acc[0][0], 0, 0, 0);
            acc[0][1] = __builtin_amdgcn_mfma_f32_32x32x16_bf16(w0, p1, acc[0][1], 0, 0, 0);
            acc[1][0] = __builtin_amdgcn_mfma_f32_32x32x16_bf16(w1, p0, acc[1][0], 0, 0, 0);
            acc[1][1] = __builtin_amdgcn_mfma_f32_32x32x16_bf16(w1, p1, acc[1][1], 0, 0, 0);
        }

        // ---- epilogue: min over 64 couts (32 in-reg + cross-half), tanh^2, store ----
        float res[2];
        #pragma unroll
        for (int n = 0; n < 2; ++n) {
            float v[16];
            #pragma unroll
            for (int r = 0; r < 16; ++r)
                v[r] = fminf(acc[0][n][r], acc[1][n][r]);   // min over the 2 M-tiles
            #pragma unroll
            for (int s = 8; s >= 1; s >>= 1)
                #pragma unroll
                for (int r = 0; r < s; ++r)
                    v[r] = fminf(v[r], v[r + s]);           // in-register tree (16 couts/half)
            res[n] = fminf(v[0], __shfl_xor(v[0], 32, 64)); // other 32 couts live in lane^32
        }
        float val = hi ? res[1] : res[0];    // lane owns pixel px_lin = wv*64 + lane
        int px_lin = wv * 64 + lane;
        int oy = ty * TS + (px_lin >> 4);
        int ox = x0 + (px_lin & 15);
        if (oy < HO && ox < WO)
            out[((size_t)b * HO + oy) * WO + ox] = fast_tanh(fast_tanh(val));

        // ---- write staged regs into the other buffer ----
        if (ty + 1 < NTY) stage_write(cur ^ 1);
        __syncthreads();
    }
}

extern "C" void kernel_launch(void* const* d_in, const int* in_sizes, int n_in,
                              void* d_out, int out_size, void* d_ws, size_t ws_size,
                              hipStream_t stream) {
    const float* x    = (const float*)d_in[0];
    const float* w    = (const float*)d_in[1];
    const float* bias = (const float*)d_in[2];
    float* out        = (float*)d_out;
    ushort* wpk       = (ushort*)d_ws;   // 9*64*16 bf16 = 18432 B

    hipLaunchKernelGGL(repack_w, dim3(36), dim3(256), 0, stream, w, wpk);
    hipLaunchKernelGGL(conv_min_tanh_strip, dim3(1024), dim3(256), 0, stream,
                       x, bias, wpk, out);
}

// Round 5
// 106.875 us; speedup vs baseline: 32.6138x; 1.2017x over previous
//
#include <hip/hip_runtime.h>
#include <hip/hip_bf16.h>

#define BATCH 64
#define CIN   16
#define H     256
#define W     256
#define HW    (H*W)
#define COUT  64
#define HO    254
#define WO    254

#define TS     16          // output tile edge
#define TIN    18          // staged input tile edge
#define CELL   24          // ushorts per (y,x) cell: 16 ci + 8 pad (48B stride, 16B-aligned)
#define NTY    8           // y-tiles per block (half strip)
#define NITEMS (4*TIN*TIN) // 1296 staging items per tile
#define IPT    6           // items per thread (5 full + 1 partial)

typedef short  bf16x8 __attribute__((ext_vector_type(8)));
typedef float  f32x16 __attribute__((ext_vector_type(16)));

static __device__ __forceinline__ unsigned short bfbits(float f) {
    __hip_bfloat16 h = __float2bfloat16(f);
    return *(unsigned short*)&h;
}

static __device__ __forceinline__ bf16x8 ld_frag(const ushort* p) {
    union { uint4 u; bf16x8 b; } cv;
    cv.u = *(const uint4*)p;
    return cv.b;
}

static __device__ __forceinline__ float fast_tanh(float x) {
    x = fminf(fmaxf(x, -15.f), 15.f);
    float e = __expf(2.f * x);
    return (e - 1.f) * __builtin_amdgcn_rcpf(e + 1.f);
}

// ---- repack weights: w[cout][ci][kh][kw] fp32 -> wpk[tap][cout][ci] bf16 ----
__global__ void repack_w(const float* __restrict__ w, ushort* __restrict__ wpk) {
    int i = blockIdx.x * 256 + threadIdx.x;
    if (i < 9 * COUT * CIN) {
        int ci   = i & 15;
        int cout = (i >> 4) & 63;
        int tap  = i >> 10;
        wpk[i] = bfbits(w[(cout * CIN + ci) * 9 + tap]);
    }
}

__global__ __launch_bounds__(256, 2)
void conv_min_tanh_strip(const float* __restrict__ x,
                         const float* __restrict__ bias,
                         const ushort* __restrict__ wpk,
                         float* __restrict__ out) {
    __shared__ __align__(16) ushort xsm[2][TIN * TIN * CELL];  // 2 x 15552 B

    // bijective XCD swizzle (2048 % 8 == 0): 256 consecutive L per XCD
    const int bid    = blockIdx.x;                 // 0..2047
    const int L      = (bid & 7) * 256 + (bid >> 3);
    const int b      = L >> 5;                     // batch image
    const int rr     = L & 31;
    const int yb0    = (rr >> 4) * (NTY * TS);     // 0 or 128
    const int x0     = (rr & 15) * TS;

    const int tid  = threadIdx.x;
    const int lane = tid & 63;
    const int wv   = tid >> 6;
    const int l31  = lane & 31;
    const int hi   = lane >> 5;       // k half: ci 0-7 vs 8-15 ; D row +4*hi

    // wave-uniform global bases for the 4 ci-planes of this image
    const float* xb0 = x + (size_t)b * (CIN * HW);
    const float* xb1 = xb0 + HW;
    const float* xb2 = xb0 + 2 * HW;
    const float* xb3 = xb0 + 3 * HW;

    // ---- weights: 18 bf16x8 frags resident in VGPRs for the whole block ----
    bf16x8 wf[9][2];
    #pragma unroll
    for (int tap = 0; tap < 9; ++tap)
        #pragma unroll
        for (int m = 0; m < 2; ++m)
            wf[tap][m] = ld_frag(wpk + tap * 1024 + (m * 32 + l31) * 16 + hi * 8);

    // per-accumulator-register bias (D row = cout = (r&3)+8*(r>>2)+4*hi + m*32)
    float bini[2][16];
    #pragma unroll
    for (int m = 0; m < 2; ++m)
        #pragma unroll
        for (int r = 0; r < 16; ++r)
            bini[m][r] = bias[m * 32 + (r & 3) + 8 * (r >> 2) + 4 * hi];

    // ---- staging address precompute (loop-invariant) ----
    // NOTE: x-clamp (min with W-1) is REQUIRED: x0+dx reaches 257 on the
    // right-edge strip; unclamped it reads past the tensor at gy=255/cg=3
    // (the round-4 crash). Clamped values only feed discarded outputs.
    int c0[IPT], dyv[IPT], lo[IPT];
    #pragma unroll
    for (int k = 0; k < IPT; ++k) {
        int it = tid + k * 256;
        int dx = it % TIN;
        int t2 = it / TIN;
        int dy = t2 % TIN;
        int cg = t2 / TIN;
        c0[k]  = cg * 4 * HW + min(x0 + dx, W - 1);  // float index within plane-group
        dyv[k] = dy;
        lo[k]  = (dy * TIN + dx) * CELL + cg * 4;    // ushort index in LDS tile
    }

    // B-frag (pixel) cell bases. N-tile n: col = pixel l31,
    // py = wv*4 + n*2 + (l31>>4), px = l31&15, k = ci = hi*8+j
    const int py_b = wv * 4 + (l31 >> 4);
    const int pxc  = l31 & 15;
    const int cb0  = ((py_b + 0) * TIN + pxc) * CELL + hi * 8;
    const int cb1  = ((py_b + 2) * TIN + pxc) * CELL + hi * 8;

    float fx[IPT][4];

    auto stage_load = [&](int ybase) {
        #pragma unroll
        for (int k = 0; k < IPT; ++k) {
            if (k < 5 || tid < NITEMS - 5 * 256) {
                int gy  = min(ybase + dyv[k], H - 1);
                int idx = c0[k] + (gy << 8);
                fx[k][0] = xb0[idx];
                fx[k][1] = xb1[idx];
                fx[k][2] = xb2[idx];
                fx[k][3] = xb3[idx];
            }
        }
    };
    auto stage_write = [&](int buf) {
        #pragma unroll
        for (int k = 0; k < IPT; ++k) {
            if (k < 5 || tid < NITEMS - 5 * 256) {
                ushort4 v;
                v.x = bfbits(fx[k][0]);
                v.y = bfbits(fx[k][1]);
                v.z = bfbits(fx[k][2]);
                v.w = bfbits(fx[k][3]);
                *(ushort4*)&xsm[buf][lo[k]] = v;
            }
        }
    };

    // ---- prologue: stage tile 0 ----
    stage_load(yb0);
    stage_write(0);
    __syncthreads();

    for (int t = 0; t < NTY; ++t) {
        const int cur = t & 1;

        // T14: issue next tile's global loads before compute
        if (t + 1 < NTY) stage_load(yb0 + (t + 1) * TS);

        f32x16 acc[2][2];
        #pragma unroll
        for (int m = 0; m < 2; ++m)
            #pragma unroll
            for (int r = 0; r < 16; ++r) {
                acc[m][0][r] = bini[m][r];
                acc[m][1][r] = bini[m][r];
            }

        const ushort* xt = &xsm[cur][0];
        #pragma unroll
        for (int tap = 0; tap < 9; ++tap) {
            const int kh = tap / 3, kw = tap - 3 * kh;
            const int toff = (kh * TIN + kw) * CELL;
            bf16x8 p0 = ld_frag(xt + cb0 + toff);
            bf16x8 p1 = ld_frag(xt + cb1 + toff);
            acc[0][0] = __builtin_amdgcn_mfma_f32_32x32x16_bf16(wf[tap][0], p0, acc[0][0], 0, 0, 0);
            acc[0][1] = __builtin_amdgcn_mfma_f32_32x32x16_bf16(wf[tap][0], p1, acc[0][1], 0, 0, 0);
            acc[1][0] = __builtin_amdgcn_mfma_f32_32x32x16_bf16(wf[tap][1], p0, acc[1][0], 0, 0, 0);
            acc[1][1] = __builtin_amdgcn_mfma_f32_32x32x16_bf16(wf[tap][1], p1, acc[1][1], 0, 0, 0);
        }

        // ---- epilogue: min over 64 couts (in-reg tree + one cross-half shfl) ----
        float res[2];
        #pragma unroll
        for (int n = 0; n < 2; ++n) {
            float v[16];
            #pragma unroll
            for (int r = 0; r < 16; ++r)
                v[r] = fminf(acc[0][n][r], acc[1][n][r]);   // min over 2 M-tiles
            #pragma unroll
            for (int s = 8; s >= 1; s >>= 1)
                #pragma unroll
                for (int r = 0; r < s; ++r)
                    v[r] = fminf(v[r], v[r + s]);
            res[n] = fminf(v[0], __shfl_xor(v[0], 32, 64)); // other 32 couts in lane^32
        }
        float val = hi ? res[1] : res[0];     // lane owns pixel px_lin = wv*64 + lane
        int px_lin = wv * 64 + lane;
        int oy = yb0 + t * TS + (px_lin >> 4);
        int ox = x0 + (px_lin & 15);
        if (oy < HO && ox < WO)
            out[((size_t)b * HO + oy) * WO + ox] = fast_tanh(fast_tanh(val));

        if (t + 1 < NTY) stage_write(cur ^ 1);
        __syncthreads();
    }
}

extern "C" void kernel_launch(void* const* d_in, const int* in_sizes, int n_in,
                              void* d_out, int out_size, void* d_ws, size_t ws_size,
                              hipStream_t stream) {
    const float* x    = (const float*)d_in[0];
    const float* w    = (const float*)d_in[1];
    const float* bias = (const float*)d_in[2];
    float* out        = (float*)d_out;
    ushort* wpk       = (ushort*)d_ws;   // 9*64*16 bf16 = 18432 B

    hipLaunchKernelGGL(repack_w, dim3(36), dim3(256), 0, stream, w, wpk);
    hipLaunchKernelGGL(conv_min_tanh_strip, dim3(2048), dim3(256), 0, stream,
                       x, bias, wpk, out);
}